// Round 4
// baseline (38.923 us; speedup 1.0000x reference)
//
#include <hip/hip_runtime.h>
#include <stdint.h>

#define G 96
#define GS (G*G)            // 9216
#define ST 104              // LDS row stride in bf16 elems (16B-aligned rows)
#define ARR (G*ST)          // 9984 elems = 19968 B per array
#define NT 256

typedef short bf16x8  __attribute__((ext_vector_type(8)));
typedef short short4v __attribute__((ext_vector_type(4)));
typedef float f32x4   __attribute__((ext_vector_type(4)));

__device__ __forceinline__ short f2bf(float f) {
  uint32_t u = __builtin_bit_cast(uint32_t, f);
  u += 0x7FFFu + ((u >> 16) & 1u);          // RNE
  return (short)(u >> 16);
}

// Proven fragment convention: af from P rows, bg from Q rows ->
// acc[i][j][r] = (P * Q^T)[wm + i*16 + (lane>>4)*4 + r][wn + j*16 + (lane&15)]
__device__ __forceinline__ void mm_phase(const short* __restrict__ P,
                                         const short* __restrict__ Q,
                                         int wm, int wn, int lr, int lq,
                                         f32x4 acc[3][3]) {
  #pragma unroll
  for (int ks = 0; ks < 3; ++ks) {
    const int k0 = ks*32 + lq*8;
    bf16x8 af[3], bg[3];
    #pragma unroll
    for (int i = 0; i < 3; ++i)
      af[i] = *reinterpret_cast<const bf16x8*>(&P[(wm + i*16 + lr)*ST + k0]);
    #pragma unroll
    for (int j = 0; j < 3; ++j)
      bg[j] = *reinterpret_cast<const bf16x8*>(&Q[(wn + j*16 + lr)*ST + k0]);
    #pragma unroll
    for (int i = 0; i < 3; ++i)
      #pragma unroll
      for (int j = 0; j < 3; ++j)
        acc[i][j] = __builtin_amdgcn_mfma_f32_16x16x32_bf16(af[i], bg[j], acc[i][j], 0, 0, 0);
  }
}

#define ZERO9(A) do { \
  _Pragma("unroll") for (int i_=0;i_<3;i_++) \
    _Pragma("unroll") for (int j_=0;j_<3;j_++) A[i_][j_] = (f32x4){0.f,0.f,0.f,0.f}; \
} while (0)

__global__ __launch_bounds__(NT, 4) void acoef_kernel(
    const float* __restrict__ x, const float* __restrict__ coef,
    float* __restrict__ out) {
  __shared__ short sm[2*ARR];     // 39936 B -> 4 WG/CU
  __shared__ float red[4][8];

  short* X  = sm;        // x bf16 row-major (alive whole kernel)
  short* R1 = sm + ARR;  // phased: x^T -> A^T (barrier-separated)

  const int tid  = threadIdx.x;
  const int b    = blockIdx.x;
  const int lane = tid & 63;
  const int w    = tid >> 6;
  const int wm   = (w >> 1) * 48;
  const int wn   = (w & 1)  * 48;
  const int lr   = lane & 15;
  const int lq   = lane >> 4;
  const int cr0  = lq * 4;

  // ---- stage x (bf16 row-major): coalesced global float4, conflict-free b64 LDS ----
  const float* xg = x + (size_t)b * GS;
  #pragma unroll
  for (int it = 0; it < 9; ++it) {
    int f = tid + it*NT;                      // float4 chunk 0..2303
    float4 v = reinterpret_cast<const float4*>(xg)[f];
    int row = f / 24, c4 = (f - row*24) * 4;
    short4v sv = {f2bf(v.x), f2bf(v.y), f2bf(v.z), f2bf(v.w)};
    *reinterpret_cast<short4v*>(&X[row*ST + c4]) = sv;
  }
  __syncthreads();

  // ---- build x^T by read-back (lane-consecutive rows -> conflict-free) ----
  #pragma unroll
  for (int it = 0; it < 9; ++it) {
    int u  = tid + it*NT;                     // 0..2303
    int r2 = u % 96, cb = (u / 96) * 4;
    short4v sv = { X[(cb+0)*ST + r2], X[(cb+1)*ST + r2],
                   X[(cb+2)*ST + r2], X[(cb+3)*ST + r2] };
    *reinterpret_cast<short4v*>(&R1[r2*ST + cb]) = sv;   // xT[r2][cb..+3]
  }
  __syncthreads();

  // ---- phase 2: accA = x^2 = A; accAT = (x^T)^2 = A^T (both in registers) ----
  f32x4 accA[3][3], accAT[3][3];
  ZERO9(accA); ZERO9(accAT);
  #pragma unroll
  for (int ks = 0; ks < 3; ++ks) {
    const int k0 = ks*32 + lq*8;
    {
      bf16x8 af[3], bg[3];
      #pragma unroll
      for (int i = 0; i < 3; ++i)
        af[i] = *reinterpret_cast<const bf16x8*>(&X [(wm + i*16 + lr)*ST + k0]);
      #pragma unroll
      for (int j = 0; j < 3; ++j)
        bg[j] = *reinterpret_cast<const bf16x8*>(&R1[(wn + j*16 + lr)*ST + k0]);
      #pragma unroll
      for (int i = 0; i < 3; ++i)
        #pragma unroll
        for (int j = 0; j < 3; ++j)
          accA[i][j] = __builtin_amdgcn_mfma_f32_16x16x32_bf16(af[i], bg[j], accA[i][j], 0, 0, 0);
    }
    {
      bf16x8 af[3], bg[3];
      #pragma unroll
      for (int i = 0; i < 3; ++i)
        af[i] = *reinterpret_cast<const bf16x8*>(&R1[(wm + i*16 + lr)*ST + k0]);
      #pragma unroll
      for (int j = 0; j < 3; ++j)
        bg[j] = *reinterpret_cast<const bf16x8*>(&X [(wn + j*16 + lr)*ST + k0]);
      #pragma unroll
      for (int i = 0; i < 3; ++i)
        #pragma unroll
        for (int j = 0; j < 3; ++j)
          accAT[i][j] = __builtin_amdgcn_mfma_f32_16x16x32_bf16(af[i], bg[j], accAT[i][j], 0, 0, 0);
    }
  }

  // t0 = tr(A) from accA diag; t2 = tr(x^4) = <A, A^T> elementwise (pure regs)
  float t0 = 0.f, t2 = 0.f;
  #pragma unroll
  for (int i = 0; i < 3; ++i)
    #pragma unroll
    for (int j = 0; j < 3; ++j) {
      const int row0 = wm + i*16 + cr0, col = wn + j*16 + lr;
      #pragma unroll
      for (int r = 0; r < 4; ++r) {
        float a = accA[i][j][r];
        if (row0 + r == col) t0 += a;
        t2 += a * accAT[i][j][r];
      }
    }
  __syncthreads();               // all x^T MFMA reads complete

  // ---- store A^T row-major into R1 (overwrite x^T): contiguous b64 ----
  #pragma unroll
  for (int i = 0; i < 3; ++i)
    #pragma unroll
    for (int j = 0; j < 3; ++j) {
      const int row0 = wm + i*16 + cr0, col = wn + j*16 + lr;
      short4v sv = {f2bf(accA[i][j][0]), f2bf(accA[i][j][1]),
                    f2bf(accA[i][j][2]), f2bf(accA[i][j][3])};
      *reinterpret_cast<short4v*>(&R1[col*ST + row0]) = sv;  // A^T[col][row0..+3]
    }
  __syncthreads();

  // ---- phase 3a: accB3 = x * A = x^3 (R1 holds A^T row-major) ----
  f32x4 accB3[3][3];
  ZERO9(accB3);
  mm_phase(X, R1, wm, wn, lr, lq, accB3);

  // t1 = tr(x^3); t3 = tr(x^5) = <A^T, B3> elementwise (pure regs)
  float t1 = 0.f, t3 = 0.f;
  #pragma unroll
  for (int i = 0; i < 3; ++i)
    #pragma unroll
    for (int j = 0; j < 3; ++j) {
      const int row0 = wm + i*16 + cr0, col = wn + j*16 + lr;
      #pragma unroll
      for (int r = 0; r < 4; ++r) {
        float v = accB3[i][j][r];
        if (row0 + r == col) t1 += v;
        t3 += accAT[i][j][r] * v;
      }
    }

  // ---- phase 3b: accB3T = A^T * x^T = (x^3)^T ----
  f32x4 accB3T[3][3];
  ZERO9(accB3T);
  mm_phase(R1, X, wm, wn, lr, lq, accB3T);

  // t4 = tr(x^6) = <B3, B3^T> elementwise (pure regs)
  float t4 = 0.f;
  #pragma unroll
  for (int i = 0; i < 3; ++i)
    #pragma unroll
    for (int j = 0; j < 3; ++j)
      #pragma unroll
      for (int r = 0; r < 4; ++r)
        t4 += accB3[i][j][r] * accB3T[i][j][r];

  // ---- reduce 5 partials across the workgroup ----
  #pragma unroll
  for (int off = 32; off > 0; off >>= 1) {
    t0 += __shfl_down(t0, off, 64);
    t1 += __shfl_down(t1, off, 64);
    t2 += __shfl_down(t2, off, 64);
    t3 += __shfl_down(t3, off, 64);
    t4 += __shfl_down(t4, off, 64);
  }
  if (lane == 0) {
    red[w][0]=t0; red[w][1]=t1; red[w][2]=t2; red[w][3]=t3; red[w][4]=t4;
  }
  __syncthreads();
  if (tid == 0) {
    float T[5];
    #pragma unroll
    for (int k = 0; k < 5; ++k) T[k] = red[0][k]+red[1][k]+red[2][k]+red[3][k];
    const float inv = 1.0f / (float)GS;
    float o = 0.f, pi = 1.f;                 // pi = numel^-i
    #pragma unroll
    for (int i = 0; i < 5; ++i) {
      float u = T[i] * inv;                  // t_i / numel
      float up = u;
      #pragma unroll
      for (int j = 0; j < 4; ++j) { o += coef[i*4+j] * up * pi; up *= u; }
      pi *= inv;
    }
    out[b] = o;
  }
}

extern "C" void kernel_launch(void* const* d_in, const int* in_sizes, int n_in,
                              void* d_out, int out_size, void* d_ws, size_t ws_size,
                              hipStream_t stream) {
  const float* x    = (const float*)d_in[0];
  const float* coef = (const float*)d_in[1];
  float* out        = (float*)d_out;
  const int batch   = in_sizes[0] / GS;
  acoef_kernel<<<batch, NT, 0, stream>>>(x, coef, out);
}

// Round 5
// 33.479 us; speedup vs baseline: 1.1626x; 1.1626x over previous
//
#include <hip/hip_runtime.h>
#include <stdint.h>

#define G 96
#define GS (G*G)            // 9216
#define ST 104              // LDS row stride in bf16 elems (16B-aligned rows, 8-bank spread)
#define ARR (G*ST)          // 9984 elems = 19968 B per array
#define NT 256

typedef short bf16x8  __attribute__((ext_vector_type(8)));
typedef short short4v __attribute__((ext_vector_type(4)));
typedef float f32x4   __attribute__((ext_vector_type(4)));

__device__ __forceinline__ short f2bf(float f) {
  uint32_t u = __builtin_bit_cast(uint32_t, f);
  u += 0x7FFFu + ((u >> 16) & 1u);          // RNE
  return (short)(u >> 16);
}

// Proven fragment convention: af from P rows, bg from Q rows ->
// acc[i][j][r] = (P * Q^T)[wm + i*16 + (lane>>4)*4 + r][wn + j*16 + (lane&15)]
__device__ __forceinline__ void mm_phase(const short* __restrict__ P,
                                         const short* __restrict__ Q,
                                         int wm, int wn, int lr, int lq,
                                         f32x4 acc[3][3]) {
  #pragma unroll
  for (int ks = 0; ks < 3; ++ks) {
    const int k0 = ks*32 + lq*8;
    bf16x8 af[3], bg[3];
    #pragma unroll
    for (int i = 0; i < 3; ++i)
      af[i] = *reinterpret_cast<const bf16x8*>(&P[(wm + i*16 + lr)*ST + k0]);
    #pragma unroll
    for (int j = 0; j < 3; ++j)
      bg[j] = *reinterpret_cast<const bf16x8*>(&Q[(wn + j*16 + lr)*ST + k0]);
    #pragma unroll
    for (int i = 0; i < 3; ++i)
      #pragma unroll
      for (int j = 0; j < 3; ++j)
        acc[i][j] = __builtin_amdgcn_mfma_f32_16x16x32_bf16(af[i], bg[j], acc[i][j], 0, 0, 0);
  }
}

#define ZERO9(A) do { \
  _Pragma("unroll") for (int i_=0;i_<3;i_++) \
    _Pragma("unroll") for (int j_=0;j_<3;j_++) A[i_][j_] = (f32x4){0.f,0.f,0.f,0.f}; \
} while (0)

// min 3 waves/EU -> VGPR cap ~170: R4's identical body spilled (60 MB scratch
// writes) under (NT,4)'s 128-reg cap; 3 WG/CU with no spill beats 4 with spill.
__global__ __launch_bounds__(NT, 3) void acoef_kernel(
    const float* __restrict__ x, const float* __restrict__ coef,
    float* __restrict__ out) {
  __shared__ short sm[2*ARR];     // 39936 B
  __shared__ float red[4][8];
  __shared__ float cf[20];

  short* X  = sm;        // x bf16 row-major (alive whole kernel)
  short* R1 = sm + ARR;  // phased: x^T -> A^T (barrier-separated)

  const int tid  = threadIdx.x;
  const int b    = blockIdx.x;
  const int lane = tid & 63;
  const int w    = tid >> 6;
  const int wm   = (w >> 1) * 48;
  const int wn   = (w & 1)  * 48;
  const int lr   = lane & 15;
  const int lq   = lane >> 4;
  const int cr0  = lq * 4;

  if (tid < 20) cf[tid] = coef[tid];         // hide coef load under whole kernel

  // ---- stage x (bf16 row-major): coalesced global float4, conflict-free b64 LDS ----
  const float* xg = x + (size_t)b * GS;
  #pragma unroll
  for (int it = 0; it < 9; ++it) {
    int f = tid + it*NT;                      // float4 chunk 0..2303
    float4 v = reinterpret_cast<const float4*>(xg)[f];
    int row = f / 24, c4 = (f - row*24) * 4;
    short4v sv = {f2bf(v.x), f2bf(v.y), f2bf(v.z), f2bf(v.w)};
    *reinterpret_cast<short4v*>(&X[row*ST + c4]) = sv;
  }
  __syncthreads();

  // ---- build x^T by read-back (reads conflict-free; writes ~8-way) ----
  #pragma unroll
  for (int it = 0; it < 9; ++it) {
    int u  = tid + it*NT;                     // 0..2303
    int r2 = u % 96, cb = (u / 96) * 4;
    short4v sv = { X[(cb+0)*ST + r2], X[(cb+1)*ST + r2],
                   X[(cb+2)*ST + r2], X[(cb+3)*ST + r2] };
    *reinterpret_cast<short4v*>(&R1[r2*ST + cb]) = sv;   // xT[r2][cb..+3]
  }
  __syncthreads();

  // ---- phase 2: accA = x^2 = A; accAT = A^T (both in registers) ----
  f32x4 accA[3][3], accAT[3][3];
  ZERO9(accA); ZERO9(accAT);
  #pragma unroll
  for (int ks = 0; ks < 3; ++ks) {
    const int k0 = ks*32 + lq*8;
    {
      bf16x8 af[3], bg[3];
      #pragma unroll
      for (int i = 0; i < 3; ++i)
        af[i] = *reinterpret_cast<const bf16x8*>(&X [(wm + i*16 + lr)*ST + k0]);
      #pragma unroll
      for (int j = 0; j < 3; ++j)
        bg[j] = *reinterpret_cast<const bf16x8*>(&R1[(wn + j*16 + lr)*ST + k0]);
      #pragma unroll
      for (int i = 0; i < 3; ++i)
        #pragma unroll
        for (int j = 0; j < 3; ++j)
          accA[i][j] = __builtin_amdgcn_mfma_f32_16x16x32_bf16(af[i], bg[j], accA[i][j], 0, 0, 0);
    }
    {
      bf16x8 af[3], bg[3];
      #pragma unroll
      for (int i = 0; i < 3; ++i)
        af[i] = *reinterpret_cast<const bf16x8*>(&R1[(wm + i*16 + lr)*ST + k0]);
      #pragma unroll
      for (int j = 0; j < 3; ++j)
        bg[j] = *reinterpret_cast<const bf16x8*>(&X [(wn + j*16 + lr)*ST + k0]);
      #pragma unroll
      for (int i = 0; i < 3; ++i)
        #pragma unroll
        for (int j = 0; j < 3; ++j)
          accAT[i][j] = __builtin_amdgcn_mfma_f32_16x16x32_bf16(af[i], bg[j], accAT[i][j], 0, 0, 0);
    }
  }

  // t0 = tr(A); t2 = tr(x^4) = <A, A^T> elementwise (pure regs)
  float t0 = 0.f, t2 = 0.f;
  #pragma unroll
  for (int i = 0; i < 3; ++i)
    #pragma unroll
    for (int j = 0; j < 3; ++j) {
      const int row0 = wm + i*16 + cr0, col = wn + j*16 + lr;
      #pragma unroll
      for (int r = 0; r < 4; ++r) {
        float a = accA[i][j][r];
        if (row0 + r == col) t0 += a;
        t2 += a * accAT[i][j][r];
      }
    }
  __syncthreads();               // all x^T MFMA reads complete

  // ---- store A^T row-major into R1 (overwrite x^T): contiguous b64; accA dies ----
  #pragma unroll
  for (int i = 0; i < 3; ++i)
    #pragma unroll
    for (int j = 0; j < 3; ++j) {
      const int row0 = wm + i*16 + cr0, col = wn + j*16 + lr;
      short4v sv = {f2bf(accA[i][j][0]), f2bf(accA[i][j][1]),
                    f2bf(accA[i][j][2]), f2bf(accA[i][j][3])};
      *reinterpret_cast<short4v*>(&R1[col*ST + row0]) = sv;  // A^T[col][row0..+3]
    }
  __syncthreads();

  // ---- phase 3a: accB3 = x * A = x^3 (R1 holds A^T row-major) ----
  f32x4 accB3[3][3];
  ZERO9(accB3);
  mm_phase(X, R1, wm, wn, lr, lq, accB3);

  // t1 = tr(x^3); t3 = tr(x^5) = <A^T, B3> elementwise; accAT dies
  float t1 = 0.f, t3 = 0.f;
  #pragma unroll
  for (int i = 0; i < 3; ++i)
    #pragma unroll
    for (int j = 0; j < 3; ++j) {
      const int row0 = wm + i*16 + cr0, col = wn + j*16 + lr;
      #pragma unroll
      for (int r = 0; r < 4; ++r) {
        float v = accB3[i][j][r];
        if (row0 + r == col) t1 += v;
        t3 += accAT[i][j][r] * v;
      }
    }

  // ---- phase 3b: accB3T = A^T * x^T = (x^3)^T ----
  f32x4 accB3T[3][3];
  ZERO9(accB3T);
  mm_phase(R1, X, wm, wn, lr, lq, accB3T);

  // t4 = tr(x^6) = <B3, B3^T> elementwise (pure regs)
  float t4 = 0.f;
  #pragma unroll
  for (int i = 0; i < 3; ++i)
    #pragma unroll
    for (int j = 0; j < 3; ++j)
      #pragma unroll
      for (int r = 0; r < 4; ++r)
        t4 += accB3[i][j][r] * accB3T[i][j][r];

  // ---- reduce 5 partials across the workgroup ----
  #pragma unroll
  for (int off = 32; off > 0; off >>= 1) {
    t0 += __shfl_down(t0, off, 64);
    t1 += __shfl_down(t1, off, 64);
    t2 += __shfl_down(t2, off, 64);
    t3 += __shfl_down(t3, off, 64);
    t4 += __shfl_down(t4, off, 64);
  }
  if (lane == 0) {
    red[w][0]=t0; red[w][1]=t1; red[w][2]=t2; red[w][3]=t3; red[w][4]=t4;
  }
  __syncthreads();
  if (tid == 0) {
    float T[5];
    #pragma unroll
    for (int k = 0; k < 5; ++k) T[k] = red[0][k]+red[1][k]+red[2][k]+red[3][k];
    const float inv = 1.0f / (float)GS;
    float o = 0.f, pi = 1.f;                 // pi = numel^-i
    #pragma unroll
    for (int i = 0; i < 5; ++i) {
      float u = T[i] * inv;                  // t_i / numel
      float up = u;
      #pragma unroll
      for (int j = 0; j < 4; ++j) { o += cf[i*4+j] * up * pi; up *= u; }
      pi *= inv;
    }
    out[b] = o;
  }
}

extern "C" void kernel_launch(void* const* d_in, const int* in_sizes, int n_in,
                              void* d_out, int out_size, void* d_ws, size_t ws_size,
                              hipStream_t stream) {
  const float* x    = (const float*)d_in[0];
  const float* coef = (const float*)d_in[1];
  float* out        = (float*)d_out;
  const int batch   = in_sizes[0] / GS;
  acoef_kernel<<<batch, NT, 0, stream>>>(x, coef, out);
}

// Round 6
// 31.480 us; speedup vs baseline: 1.2364x; 1.0635x over previous
//
#include <hip/hip_runtime.h>
#include <stdint.h>

#define G 96
#define GS (G*G)            // 9216
#define ST 104              // LDS row stride in bf16 elems (16B-aligned rows)
#define ARR (G*ST)          // 9984 elems = 19968 B per array
#define NT 256

typedef short bf16x8  __attribute__((ext_vector_type(8)));
typedef short short4v __attribute__((ext_vector_type(4)));
typedef float f32x4   __attribute__((ext_vector_type(4)));

__device__ __forceinline__ short f2bf(float f) {
  uint32_t u = __builtin_bit_cast(uint32_t, f);
  u += 0x7FFFu + ((u >> 16) & 1u);          // RNE
  return (short)(u >> 16);
}
__device__ __forceinline__ float bf2f(short s) {
  uint32_t u = ((uint32_t)(uint16_t)s) << 16;
  return __builtin_bit_cast(float, u);
}

// Proven fragment convention: af from P rows, bg from Q rows ->
// acc[i][j][r] = (P * Q^T)[wm + i*16 + (lane>>4)*4 + r][wn + j*16 + (lane&15)]
__device__ __forceinline__ void mm_phase(const short* __restrict__ P,
                                         const short* __restrict__ Q,
                                         int wm, int wn, int lr, int lq,
                                         f32x4 acc[3][3]) {
  #pragma unroll
  for (int ks = 0; ks < 3; ++ks) {
    const int k0 = ks*32 + lq*8;
    bf16x8 af[3], bg[3];
    #pragma unroll
    for (int i = 0; i < 3; ++i)
      af[i] = *reinterpret_cast<const bf16x8*>(&P[(wm + i*16 + lr)*ST + k0]);
    #pragma unroll
    for (int j = 0; j < 3; ++j)
      bg[j] = *reinterpret_cast<const bf16x8*>(&Q[(wn + j*16 + lr)*ST + k0]);
    #pragma unroll
    for (int i = 0; i < 3; ++i)
      #pragma unroll
      for (int j = 0; j < 3; ++j)
        acc[i][j] = __builtin_amdgcn_mfma_f32_16x16x32_bf16(af[i], bg[j], acc[i][j], 0, 0, 0);
  }
}

#define ZERO9(A) do { \
  _Pragma("unroll") for (int i_=0;i_<3;i_++) \
    _Pragma("unroll") for (int j_=0;j_<3;j_++) A[i_][j_] = (f32x4){0.f,0.f,0.f,0.f}; \
} while (0)

// 3-pass trace decomposition: A=x^2, B3=x^3, A2=A^2.
// t0=tr(A), t1=tr(B3), t2=tr(A2)=tr(x^4), t3=tr(B3*A)=tr(x^5), t4=tr(A2*A)=tr(x^6).
// t3,t4 share one b64 partner read A[col][row0+r]; max 2 acc arrays live.
__global__ __launch_bounds__(NT, 4) void acoef_kernel(
    const float* __restrict__ x, const float* __restrict__ coef,
    float* __restrict__ out) {
  __shared__ short sm[2*ARR];     // 39936 B -> 4 WG/CU
  __shared__ float red[4][8];
  __shared__ float cf[20];

  short* X  = sm;        // x row-major -> (after phase B) A row-major
  short* R1 = sm + ARR;  // x^T -> A^T (barrier-separated)

  const int tid  = threadIdx.x;
  const int b    = blockIdx.x;
  const int lane = tid & 63;
  const int w    = tid >> 6;
  const int wm   = (w >> 1) * 48;
  const int wn   = (w & 1)  * 48;
  const int lr   = lane & 15;
  const int lq   = lane >> 4;
  const int cr0  = lq * 4;

  if (tid < 20) cf[tid] = coef[tid];

  // ---- stage x (bf16 row-major) ----
  const float* xg = x + (size_t)b * GS;
  #pragma unroll
  for (int it = 0; it < 9; ++it) {
    int f = tid + it*NT;
    float4 v = reinterpret_cast<const float4*>(xg)[f];
    int row = f / 24, c4 = (f - row*24) * 4;
    short4v sv = {f2bf(v.x), f2bf(v.y), f2bf(v.z), f2bf(v.w)};
    *reinterpret_cast<short4v*>(&X[row*ST + c4]) = sv;
  }
  __syncthreads();                                    // B1

  // ---- build x^T by read-back ----
  #pragma unroll
  for (int it = 0; it < 9; ++it) {
    int u  = tid + it*NT;
    int r2 = u % 96, cb = (u / 96) * 4;
    short4v sv = { X[(cb+0)*ST + r2], X[(cb+1)*ST + r2],
                   X[(cb+2)*ST + r2], X[(cb+3)*ST + r2] };
    *reinterpret_cast<short4v*>(&R1[r2*ST + cb]) = sv;
  }
  __syncthreads();                                    // B2

  // ---- phase A: accA = x * x = A ----
  f32x4 accA[3][3];
  ZERO9(accA);
  mm_phase(X, R1, wm, wn, lr, lq, accA);

  float t0 = 0.f;
  #pragma unroll
  for (int i = 0; i < 3; ++i)
    #pragma unroll
    for (int j = 0; j < 3; ++j) {
      const int row0 = wm + i*16 + cr0, col = wn + j*16 + lr;
      #pragma unroll
      for (int r = 0; r < 4; ++r)
        if (row0 + r == col) t0 += accA[i][j][r];
    }
  __syncthreads();                                    // B3 (x^T dead)

  // ---- store A^T row-major into R1: contiguous b64 ----
  #pragma unroll
  for (int i = 0; i < 3; ++i)
    #pragma unroll
    for (int j = 0; j < 3; ++j) {
      const int row0 = wm + i*16 + cr0, col = wn + j*16 + lr;
      short4v sv = {f2bf(accA[i][j][0]), f2bf(accA[i][j][1]),
                    f2bf(accA[i][j][2]), f2bf(accA[i][j][3])};
      *reinterpret_cast<short4v*>(&R1[col*ST + row0]) = sv;
    }
  __syncthreads();                                    // B4 (A^T ready)

  // ---- phase B: accB3 = x * A = x^3 ----
  f32x4 accB3[3][3];
  ZERO9(accB3);
  mm_phase(X, R1, wm, wn, lr, lq, accB3);

  float t1 = 0.f;
  #pragma unroll
  for (int i = 0; i < 3; ++i)
    #pragma unroll
    for (int j = 0; j < 3; ++j) {
      const int row0 = wm + i*16 + cr0, col = wn + j*16 + lr;
      #pragma unroll
      for (int r = 0; r < 4; ++r)
        if (row0 + r == col) t1 += accB3[i][j][r];
    }
  __syncthreads();                                    // B5 (X dead)

  // ---- store A row-major over X: 36 scalar w16 (lanes span cols -> ~4-way) ----
  #pragma unroll
  for (int i = 0; i < 3; ++i)
    #pragma unroll
    for (int j = 0; j < 3; ++j) {
      const int row0 = wm + i*16 + cr0, col = wn + j*16 + lr;
      #pragma unroll
      for (int r = 0; r < 4; ++r)
        X[(row0+r)*ST + col] = f2bf(accA[i][j][r]);
    }
  __syncthreads();                                    // B6 (A-row ready)

  // ---- partner reads A[col][row0+r] (shared by t3 and t4), then t3 ----
  short4v pr[3][3];
  float t3 = 0.f;
  #pragma unroll
  for (int i = 0; i < 3; ++i)
    #pragma unroll
    for (int j = 0; j < 3; ++j) {
      const int row0 = wm + i*16 + cr0, col = wn + j*16 + lr;
      pr[i][j] = *reinterpret_cast<const short4v*>(&X[col*ST + row0]);
      #pragma unroll
      for (int r = 0; r < 4; ++r)
        t3 += accB3[i][j][r] * bf2f(pr[i][j][r]);     // tr(x^5); accB3 dies
    }

  // ---- phase C: accA2 = A * A = x^4 (af from X=A rows, bg from R1=A^T) ----
  f32x4 accA2[3][3];
  ZERO9(accA2);
  mm_phase(X, R1, wm, wn, lr, lq, accA2);

  float t2 = 0.f, t4 = 0.f;
  #pragma unroll
  for (int i = 0; i < 3; ++i)
    #pragma unroll
    for (int j = 0; j < 3; ++j) {
      const int row0 = wm + i*16 + cr0, col = wn + j*16 + lr;
      #pragma unroll
      for (int r = 0; r < 4; ++r) {
        float v = accA2[i][j][r];
        if (row0 + r == col) t2 += v;                 // tr(x^4)
        t4 += v * bf2f(pr[i][j][r]);                  // tr(x^6) = tr(A^2 * A)
      }
    }

  // ---- reduce 5 partials across the workgroup ----
  #pragma unroll
  for (int off = 32; off > 0; off >>= 1) {
    t0 += __shfl_down(t0, off, 64);
    t1 += __shfl_down(t1, off, 64);
    t2 += __shfl_down(t2, off, 64);
    t3 += __shfl_down(t3, off, 64);
    t4 += __shfl_down(t4, off, 64);
  }
  if (lane == 0) {
    red[w][0]=t0; red[w][1]=t1; red[w][2]=t2; red[w][3]=t3; red[w][4]=t4;
  }
  __syncthreads();                                    // B7
  if (tid == 0) {
    float T[5];
    #pragma unroll
    for (int k = 0; k < 5; ++k) T[k] = red[0][k]+red[1][k]+red[2][k]+red[3][k];
    const float inv = 1.0f / (float)GS;
    float o = 0.f, pi = 1.f;
    #pragma unroll
    for (int i = 0; i < 5; ++i) {
      float u = T[i] * inv;
      float up = u;
      #pragma unroll
      for (int j = 0; j < 4; ++j) { o += cf[i*4+j] * up * pi; up *= u; }
      pi *= inv;
    }
    out[b] = o;
  }
}

extern "C" void kernel_launch(void* const* d_in, const int* in_sizes, int n_in,
                              void* d_out, int out_size, void* d_ws, size_t ws_size,
                              hipStream_t stream) {
  const float* x    = (const float*)d_in[0];
  const float* coef = (const float*)d_in[1];
  float* out        = (float*)d_out;
  const int batch   = in_sizes[0] / GS;
  acoef_kernel<<<batch, NT, 0, stream>>>(x, coef, out);
}